// Round 2
// 220.160 us; speedup vs baseline: 1.0215x; 1.0215x over previous
//
#include <hip/hip_runtime.h>
#include <cstdint>
#include <cstddef>

typedef _Float16 half_t;
typedef _Float16 half8 __attribute__((ext_vector_type(8)));
typedef _Float16 half4v __attribute__((ext_vector_type(4)));
typedef float float4_ __attribute__((ext_vector_type(4)));

#define NB 8
#define SEQ 2048
#define DIM 256
#define NROWS (NB*SEQ)   // 16384
#define KS 4             // k-split -> grid 512 = 2 blocks/CU
#define NIT 16           // (2048/KS)/32 key-tiles per block

// async global->LDS DMA, 16B per lane; LDS dest = wave-uniform base + lane*16
__device__ __forceinline__ void dma16(const half_t* g, half_t* l) {
    __builtin_amdgcn_global_load_lds(
        (const __attribute__((address_space(1))) void*)g,
        (__attribute__((address_space(3))) void*)l,
        16, 0, 0);
}

// ---------------------------------------------------------------------------
// Kernel 1: fold Wc = Wa @ Wk, bc = Wa @ bk + ba; split weights to fp16 hi/lo
// ---------------------------------------------------------------------------
__global__ __launch_bounds__(256) void prep_kernel(
    const float* __restrict__ Wq, const float* __restrict__ Wk,
    const float* __restrict__ Wv, const float* __restrict__ Wa,
    const float* __restrict__ bk, const float* __restrict__ ba,
    half_t* __restrict__ Wq_hi, half_t* __restrict__ Wq_lo,
    half_t* __restrict__ Wc_hi, half_t* __restrict__ Wc_lo,
    half_t* __restrict__ Wv_hi, float* __restrict__ bc)
{
    const int e = blockIdx.x;
    const int d = threadIdx.x;
    const int idx = e * 256 + d;
    float acc = 0.f;
    for (int m = 0; m < 256; ++m)
        acc += Wa[e * 256 + m] * Wk[m * 256 + d];
    half_t h = (half_t)acc;
    Wc_hi[idx] = h;
    Wc_lo[idx] = (half_t)(acc - (float)h);
    float wq = Wq[idx];
    h = (half_t)wq;
    Wq_hi[idx] = h;
    Wq_lo[idx] = (half_t)(wq - (float)h);
    Wv_hi[idx] = (half_t)Wv[idx];
    if (d == 0) {
        float bacc = ba[e];
        for (int m = 0; m < 256; ++m) bacc += Wa[e * 256 + m] * bk[m];
        bc[e] = bacc;
    }
}

// ---------------------------------------------------------------------------
// Kernel 2: linears. seg0: q hi only (q_lo dropped). seg1: wk hi/lo written
// in ATTN-TILE-SWIZZLED global layout (32-key tiles, chunk pos = c^(s&7)) so
// the attention kernel can stage via identity global_load_lds DMA. seg2: v ->
// vT in tile-swizzled layout (slot = sc^(d&3)^((d>>2)&3)); the KEY axis inside
// each logical chunk q is PERMUTED: slot-chunk q holds keys {4q..4q+3} u
// {16+4q..16+4q+3} so attn's P feeds PV directly from registers (no LDS P buf).
// ---------------------------------------------------------------------------
__global__ __launch_bounds__(256, 1) void linear_kernel(
    const float* __restrict__ x, const float* __restrict__ states,
    const half_t* __restrict__ Wq_hi, const half_t* __restrict__ Wq_lo, const float* __restrict__ bq,
    const half_t* __restrict__ Wc_hi, const half_t* __restrict__ Wc_lo, const float* __restrict__ bc,
    const half_t* __restrict__ Wv_hi, const float* __restrict__ bv,
    half_t* __restrict__ q_hi,
    half_t* __restrict__ wk_hi, half_t* __restrict__ wk_lo,
    half_t* __restrict__ vT)
{
    __shared__ half_t sB[2 * 64 * 256];   // weights hi+lo = 64 KiB; reused as repack buf
    half_t* sBh = sB;
    half_t* sBl = sB + 64 * 256;

    const int seg  = blockIdx.x >> 8;      // 0:q 1:wk 2:v
    const int t    = blockIdx.x & 255;
    const int tid  = threadIdx.x;
    const int lane = tid & 63;
    const int wv   = tid >> 6;
    const int quad = lane >> 4;
    const int l15  = lane & 15;
    const int rb   = t * 64;               // block row base
    const int r0   = rb + wv * 16;         // wave's 16 rows

    const float* src  = (seg == 0) ? x : states;
    const half_t* Bh  = (seg == 0) ? Wq_hi : (seg == 1) ? Wc_hi : Wv_hi;
    const half_t* Bl  = (seg == 0) ? Wq_lo : Wc_lo;
    const float* bias = (seg == 0) ? bq : (seg == 1) ? bc : bv;

    // A-frags direct from global: A[m=l15 -> row][k=c*32+quad*8+j], hi/lo split
    half8 ah[8], al[8];
    #pragma unroll
    for (int c = 0; c < 8; ++c) {
        const float* pa = src + (size_t)(r0 + l15) * 256 + c * 32 + quad * 8;
        float4_ u0 = *(const float4_*)pa;
        float4_ u1 = *(const float4_*)(pa + 4);
        #pragma unroll
        for (int j = 0; j < 4; ++j) {
            half_t hh = (half_t)u0[j];
            ah[c][j] = hh; al[c][j] = (half_t)(u0[j] - (float)hh);
            hh = (half_t)u1[j];
            ah[c][4 + j] = hh; al[c][4 + j] = (half_t)(u1[j] - (float)hh);
        }
    }

    float4_ acc[16];
    if (seg != 2) {
        #pragma unroll
        for (int nt = 0; nt < 16; ++nt) {
            float be = bias[nt * 16 + l15];
            acc[nt] = {be, be, be, be};
        }
    } else {
        #pragma unroll
        for (int et = 0; et < 16; ++et)
            #pragma unroll
            for (int r = 0; r < 4; ++r)
                acc[et][r] = bias[et * 16 + quad * 4 + r];
    }

    #pragma unroll
    for (int eg = 0; eg < 4; ++eg) {
        __syncthreads();
        // stage weights e-group [64 e][256 k], XOR-swizzled chunks
        #pragma unroll
        for (int i = 0; i < 8; ++i) {
            int g = tid + i * 256;             // 0..2047 chunks
            int e = g >> 5, c = g & 31;
            *(half8*)(sBh + e * 256 + ((c ^ (e & 7)) * 8)) =
                *(const half8*)(Bh + (size_t)(eg * 64 + e) * 256 + c * 8);
        }
        if (seg != 2) {
            #pragma unroll
            for (int i = 0; i < 8; ++i) {
                int g = tid + i * 256;
                int e = g >> 5, c = g & 31;
                *(half8*)(sBl + e * 256 + ((c ^ (e & 7)) * 8)) =
                    *(const half8*)(Bl + (size_t)(eg * 64 + e) * 256 + c * 8);
            }
        }
        __syncthreads();

        if (seg != 2) {
            #pragma unroll
            for (int ntl = 0; ntl < 4; ++ntl) {
                float4_ a = acc[eg * 4 + ntl];
                const int el = ntl * 16 + l15;
                #pragma unroll
                for (int c = 0; c < 8; ++c) {
                    int off = el * 256 + (((c * 4 + quad) ^ (el & 7)) * 8);
                    half8 bh = *(const half8*)(sBh + off);
                    half8 bl = *(const half8*)(sBl + off);
                    a = __builtin_amdgcn_mfma_f32_16x16x32_f16(ah[c], bh, a, 0, 0, 0);
                    a = __builtin_amdgcn_mfma_f32_16x16x32_f16(al[c], bh, a, 0, 0, 0);
                    a = __builtin_amdgcn_mfma_f32_16x16x32_f16(ah[c], bl, a, 0, 0, 0);
                }
                acc[eg * 4 + ntl] = a;
            }
        } else {
            // flipped: A = Wv tile (rows e), B = x rows -> D[e][row]
            #pragma unroll
            for (int ntl = 0; ntl < 4; ++ntl) {
                float4_ a = acc[eg * 4 + ntl];
                const int el = ntl * 16 + l15;
                #pragma unroll
                for (int c = 0; c < 8; ++c) {
                    int off = el * 256 + (((c * 4 + quad) ^ (el & 7)) * 8);
                    half8 aw = *(const half8*)(sBh + off);
                    a = __builtin_amdgcn_mfma_f32_16x16x32_f16(aw, ah[c], a, 0, 0, 0);
                }
                acc[eg * 4 + ntl] = a;
            }
        }
    }

    // epilogue: repack through LDS for coalesced half8 global stores
    __syncthreads();   // weights LDS no longer needed
    if (seg != 2) {
        half_t* R = sB;   // [64 rows][256]
        #pragma unroll
        for (int nt = 0; nt < 16; ++nt)
            #pragma unroll
            for (int r = 0; r < 4; ++r)
                R[(wv * 16 + quad * 4 + r) * 256 + nt * 16 + l15] = (half_t)acc[nt][r];
        __syncthreads();
        if (seg == 0) {
            // q hi only, row-major
            for (int i = 0; i < 8; ++i) {
                int g = tid + i * 256;                 // 2048 chunks
                int row = g >> 5, cc = g & 31;
                *(half8*)(q_hi + (size_t)(rb + row) * 256 + cc * 8) =
                    *(const half8*)(R + row * 256 + cc * 8);
            }
        } else {
            // wk hi: tile-swizzled layout (tile=32 keys, 8192 elems)
            for (int i = 0; i < 8; ++i) {
                int g = tid + i * 256;
                int row = g >> 5, cc = g & 31;
                int s = row & 31;
                size_t dst = ((size_t)(rb + row) >> 5) * 8192 + s * 256 + ((cc ^ (s & 7)) * 8);
                *(half8*)(wk_hi + dst) = *(const half8*)(R + row * 256 + cc * 8);
            }
            __syncthreads();
            #pragma unroll
            for (int nt = 0; nt < 16; ++nt)
                #pragma unroll
                for (int r = 0; r < 4; ++r) {
                    float v = acc[nt][r];
                    half_t hh = (half_t)v;
                    R[(wv * 16 + quad * 4 + r) * 256 + nt * 16 + l15] = (half_t)(v - (float)hh);
                }
            __syncthreads();
            for (int i = 0; i < 8; ++i) {
                int g = tid + i * 256;
                int row = g >> 5, cc = g & 31;
                int s = row & 31;
                size_t dst = ((size_t)(rb + row) >> 5) * 8192 + s * 256 + ((cc ^ (s & 7)) * 8);
                *(half8*)(wk_lo + dst) = *(const half8*)(R + row * 256 + cc * 8);
            }
        }
    } else {
        // vT repack: sV [d 256][s 64] stride 68, then tile-swizzled stores.
        // Key permutation: logical chunk q of a 32-key tile holds keys
        // {t32+4q+j}(j<4) and {t32+16+4q+(j-4)}(j>=4) -- matches the natural
        // per-lane P ownership of the attn QK^T output (lane quad q holds
        // keys 4q..4q+3 of kt0 and kt1).
        half_t* sV = sB;
        #pragma unroll
        for (int et = 0; et < 16; ++et)
            #pragma unroll
            for (int r = 0; r < 4; ++r)
                sV[(et * 16 + quad * 4 + r) * 68 + wv * 16 + l15] = (half_t)acc[et][r];
        __syncthreads();
        const int b = rb >> 11, s0 = rb & 2047;
        for (int i = 0; i < 8; ++i) {
            int g = tid + i * 256;                 // 2048 chunks: d 256 x sc8 8
            int d = g >> 3, sc8 = g & 7;
            int kt = (s0 >> 5) + (sc8 >> 2);
            int q  = sc8 & 3;                      // logical key-chunk
            int t32 = (sc8 >> 2) * 32;
            int slot = q ^ (d & 3) ^ ((d >> 2) & 3);
            half4v a4 = *(const half4v*)(sV + d * 68 + t32 + q * 4);
            half4v b4 = *(const half4v*)(sV + d * 68 + t32 + 16 + q * 4);
            half8 hv;
            hv[0] = a4[0]; hv[1] = a4[1]; hv[2] = a4[2]; hv[3] = a4[3];
            hv[4] = b4[0]; hv[5] = b4[1]; hv[6] = b4[2]; hv[7] = b4[3];
            size_t dst = ((size_t)b * 64 + kt) * 8192 + d * 32 + slot * 8;
            *(half8*)(vT + dst) = hv;
        }
    }
}

// ---------------------------------------------------------------------------
// Kernel 3: flash attention, software-pipelined staging.
//   - wk hi/lo single-buffered (32 KiB): re-staged for tile t+1 while softmax
//     + PV of tile t run (it is only read by QK).
//   - vT double-buffered (2 x 16 KiB): staged for tile t+1, streams under
//     softmax/PV/next-QK.
//   - RAW __builtin_amdgcn_s_barrier() + counted s_waitcnt vmcnt(N); exactly
//     12 VMEM ops issued per loop iteration makes the counts exact. Full
//     vmcnt(0) drain only in the prologue and last iteration.
//   - sched_barrier(0) pins each MFMA cluster (and its compiler-inserted
//     lgkm waits) above the following fence -- rule #18 hazard guard.
//   - P never touches LDS: producer-side key permutation of vT makes the PV
//     B-frag identical to the lane-local QK^T output.
//   - defer-rescale (THR=8): skip ctx rescale + max update when tile max is
//     within 8 of the running max (wave-uniform).
// ---------------------------------------------------------------------------
__global__ __launch_bounds__(256, 2) void attn_kernel(
    const half_t* __restrict__ q_hi,
    const half_t* __restrict__ wk_hi, const half_t* __restrict__ wk_lo,
    const half_t* __restrict__ vT,
    half_t* __restrict__ pc, float* __restrict__ pm, float* __restrict__ pl)
{
    __shared__ __align__(16) unsigned char smem[64 * 1024];
    half_t* s_wk_hi = (half_t*)smem;                  // [32 key][256 k] swizzled image
    half_t* s_wk_lo = (half_t*)(smem + 16384);
    // s_vt double buffer at smem+32768 / smem+49152: [256 d][32 key] swizzled
    float*  scr     = (float*)smem;                   // epilogue overlay

    const int tid  = threadIdx.x;
    const int lane = tid & 63;
    const int wv   = tid >> 6;
    const int quad = lane >> 4;
    const int l15  = lane & 15;

    const int b  = blockIdx.x & 7;          // XCD-swizzle: batch per XCD
    const int qt = (blockIdx.x >> 3) & 15;  // q-tile 0..15 (128 rows each)
    const int ks = blockIdx.x >> 7;         // k-split quarter 0..3

    const int qbase = b * 2048 + qt * 128 + wv * 32;   // wave's 32 q-rows

    // q B-frags resident (hi plane only): B[n=qcol][k=c*32+quad*8+j]
    half8 qf[2][8];
    #pragma unroll
    for (int ct = 0; ct < 2; ++ct)
        #pragma unroll
        for (int c = 0; c < 8; ++c)
            qf[ct][c] = *(const half8*)(q_hi +
                (size_t)(qbase + ct * 16 + l15) * 256 + c * 32 + quad * 8);

    float4_ ctx[16][2];
    #pragma unroll
    for (int dt = 0; dt < 16; ++dt) {
        ctx[dt][0] = {0.f, 0.f, 0.f, 0.f};
        ctx[dt][1] = {0.f, 0.f, 0.f, 0.f};
    }
    float m_c[2] = {-1e30f, -1e30f};
    float l_c[2] = {0.f, 0.f};

    const half_t* wkh_b = wk_hi + (size_t)b * 64 * 8192;  // tiled layout
    const half_t* wkl_b = wk_lo + (size_t)b * 64 * 8192;
    const half_t* vt_b  = vT    + (size_t)b * 64 * 8192;
    const int t0 = ks * NIT;

    // prologue: stage tile 0 fully, one-time full drain (makes the loop's
    // counted waits exact regardless of where the compiler put the qf loads).
    {
        const half_t* wh_t = wkh_b + (size_t)t0 * 8192;
        const half_t* wl_t = wkl_b + (size_t)t0 * 8192;
        #pragma unroll
        for (int i = 0; i < 4; ++i) {
            const int sg = i * 4 + wv;            // 16 segments of 1 KiB each
            dma16(wh_t + sg * 512 + lane * 8, s_wk_hi + sg * 512);
            dma16(wl_t + sg * 512 + lane * 8, s_wk_lo + sg * 512);
        }
        const half_t* vt_t = vt_b + (size_t)t0 * 8192;
        half_t* v0 = (half_t*)(smem + 32768);
        #pragma unroll
        for (int i = 0; i < 4; ++i) {
            const int sg = i * 4 + wv;
            dma16(vt_t + sg * 512 + lane * 8, v0 + sg * 512);
        }
    }
    asm volatile("s_waitcnt vmcnt(0)" ::: "memory");
    __builtin_amdgcn_s_barrier();
    asm volatile("" ::: "memory");

    for (int it = 0; it < NIT; ++it) {
        half_t* vcur = (half_t*)(smem + 32768 + ((it & 1) << 14));
        half_t* vnxt = (half_t*)(smem + 32768 + (((it & 1) ^ 1) << 14));

        // ---- S^T = wk . q^T : tiles [kt 16-keys][ct 16-qcols], hi/lo on wk
        float4_ S[2][2];
        S[0][0] = {0.f,0.f,0.f,0.f}; S[0][1] = {0.f,0.f,0.f,0.f};
        S[1][0] = {0.f,0.f,0.f,0.f}; S[1][1] = {0.f,0.f,0.f,0.f};
        __builtin_amdgcn_s_setprio(1);
        #pragma unroll
        for (int c = 0; c < 8; ++c)
            #pragma unroll
            for (int kt = 0; kt < 2; ++kt) {
                const int key = kt * 16 + l15;
                const int off = key * 256 + (((c * 4 + quad) ^ (key & 7)) * 8);
                half8 wh = *(const half8*)(s_wk_hi + off);
                half8 wl = *(const half8*)(s_wk_lo + off);
                #pragma unroll
                for (int ct = 0; ct < 2; ++ct) {
                    S[kt][ct] = __builtin_amdgcn_mfma_f32_16x16x32_f16(wh, qf[ct][c], S[kt][ct], 0, 0, 0);
                    S[kt][ct] = __builtin_amdgcn_mfma_f32_16x16x32_f16(wl, qf[ct][c], S[kt][ct], 0, 0, 0);
                }
            }
        __builtin_amdgcn_s_setprio(0);

        // pin QK MFMAs + their lgkm waits above barrier A (rule #18 guard)
        __builtin_amdgcn_sched_barrier(0);
        __builtin_amdgcn_s_barrier();        // (A) all waves done reading s_wk
        asm volatile("" ::: "memory");

        const bool pre = (it + 1 < NIT);
        if (pre) {
            // stage tile it+1: wk into the just-freed buffer, vt into vnxt.
            // Exactly 12 VMEM ops -- the counted waits below depend on this.
            const int ktn = t0 + it + 1;
            const half_t* wh_t = wkh_b + (size_t)ktn * 8192;
            const half_t* wl_t = wkl_b + (size_t)ktn * 8192;
            #pragma unroll
            for (int i = 0; i < 4; ++i) {
                const int sg = i * 4 + wv;
                dma16(wh_t + sg * 512 + lane * 8, s_wk_hi + sg * 512);
                dma16(wl_t + sg * 512 + lane * 8, s_wk_lo + sg * 512);
            }
            const half_t* vt_t = vt_b + (size_t)ktn * 8192;
            #pragma unroll
            for (int i = 0; i < 4; ++i) {
                const int sg = i * 4 + wv;
                dma16(vt_t + sg * 512 + lane * 8, vnxt + sg * 512);
            }
        }

        // ---- softmax (VALU, overlaps DMA flight); lane owns qcol ct*16+l15
        float mx0, mx1;
        {
            float a0 = fmaxf(fmaxf(S[0][0][0], S[0][0][1]), fmaxf(S[0][0][2], S[0][0][3]));
            float b0 = fmaxf(fmaxf(S[1][0][0], S[1][0][1]), fmaxf(S[1][0][2], S[1][0][3]));
            mx0 = fmaxf(a0, b0);
            mx0 = fmaxf(mx0, __shfl_xor(mx0, 16));
            mx0 = fmaxf(mx0, __shfl_xor(mx0, 32));
            float a1 = fmaxf(fmaxf(S[0][1][0], S[0][1][1]), fmaxf(S[0][1][2], S[0][1][3]));
            float b1 = fmaxf(fmaxf(S[1][1][0], S[1][1][1]), fmaxf(S[1][1][2], S[1][1][3]));
            mx1 = fmaxf(a1, b1);
            mx1 = fmaxf(mx1, __shfl_xor(mx1, 16));
            mx1 = fmaxf(mx1, __shfl_xor(mx1, 32));
        }
        // defer-rescale: keep frozen max while tile max within THR=8 (P<=e^8
        // fits fp16; l,ctx are fp32; combine handles non-max m).
        const int doresc = __any((mx0 > m_c[0] + 8.f) || (mx1 > m_c[1] + 8.f));
        float alpha0 = 1.f, alpha1 = 1.f;
        if (doresc) {
            float mn0 = fmaxf(m_c[0], mx0);
            float mn1 = fmaxf(m_c[1], mx1);
            alpha0 = __expf(m_c[0] - mn0);
            alpha1 = __expf(m_c[1] - mn1);
            m_c[0] = mn0; m_c[1] = mn1;
        }
        // P stays in registers: pf[ct] is directly the PV B-frag thanks to the
        // producer-side key permutation (slot 8q+j <-> key 4q+j / 16+4q+(j-4)).
        half8 pf[2];
        #pragma unroll
        for (int ct = 0; ct < 2; ++ct) {
            const float mm = m_c[ct];
            float rs = 0.f;
            #pragma unroll
            for (int r = 0; r < 4; ++r) {
                float p0 = __expf(S[0][ct][r] - mm);
                float p1 = __expf(S[1][ct][r] - mm);
                rs += p0 + p1;
                pf[ct][r]     = (half_t)p0;
                pf[ct][4 + r] = (half_t)p1;
            }
            rs += __shfl_xor(rs, 16);
            rs += __shfl_xor(rs, 32);
            l_c[ct] = l_c[ct] * (ct ? alpha1 : alpha0) + rs;
        }
        if (doresc) {
            #pragma unroll
            for (int dt = 0; dt < 16; ++dt)
                #pragma unroll
                for (int r = 0; r < 4; ++r) {
                    ctx[dt][0][r] *= alpha0;
                    ctx[dt][1][r] *= alpha1;
                }
        }

        // vt(it) must be resident; wk(it+1)+vt(it+1) (12 ops) stay in flight.
        if (pre) asm volatile("s_waitcnt vmcnt(12)" ::: "memory");
        else     asm volatile("s_waitcnt vmcnt(0)"  ::: "memory");
        __builtin_amdgcn_s_barrier();        // (B) publish vt(it)
        asm volatile("" ::: "memory");

        // ---- ctx^T += vT_tile . P^T
        __builtin_amdgcn_s_setprio(1);
        #pragma unroll
        for (int dt = 0; dt < 16; ++dt) {
            const int d = dt * 16 + l15;
            half8 vf = *(const half8*)(vcur + d * 32 + ((quad ^ (d & 3) ^ ((d >> 2) & 3)) * 8));
            ctx[dt][0] = __builtin_amdgcn_mfma_f32_16x16x32_f16(vf, pf[0], ctx[dt][0], 0, 0, 0);
            ctx[dt][1] = __builtin_amdgcn_mfma_f32_16x16x32_f16(vf, pf[1], ctx[dt][1], 0, 0, 0);
        }
        __builtin_amdgcn_s_setprio(0);

        // pin PV MFMAs + their lgkm waits above barrier C (rule #18 guard)
        __builtin_amdgcn_sched_barrier(0);
        // wk(it+1) must be resident before next QK; vt(it+1) (4) stays in flight.
        if (pre) asm volatile("s_waitcnt vmcnt(4)" ::: "memory");
        __builtin_amdgcn_s_barrier();        // (C) publish wk(it+1); vcur reusable
        asm volatile("" ::: "memory");
    }

    // epilogue: normalized partial context (fp16) via per-wave LDS transpose.
    // Barrier (C) of the last iteration guarantees all waves are past PV.
    float rinv[2] = {1.0f / l_c[0], 1.0f / l_c[1]};
    float* sw = scr + wv * (32 * 68);       // [q 32][stride 68] f32
    half_t* pcs = pc + (size_t)ks * NROWS * 256;
    #pragma unroll
    for (int rd = 0; rd < 4; ++rd) {
        #pragma unroll
        for (int dtl = 0; dtl < 4; ++dtl) {
            const int dt = rd * 4 + dtl;
            #pragma unroll
            for (int ct = 0; ct < 2; ++ct)
                #pragma unroll
                for (int r = 0; r < 4; ++r)
                    sw[(ct * 16 + l15) * 68 + dtl * 16 + quad * 4 + r] = ctx[dt][ct][r] * rinv[ct];
        }
        #pragma unroll
        for (int i = 0; i < 8; ++i) {
            int g = lane + i * 64;
            int q = g >> 4, dc = g & 15;
            float4_ v4 = *(const float4_*)(sw + q * 68 + dc * 4);
            half4v h4;
            #pragma unroll
            for (int j = 0; j < 4; ++j) h4[j] = (half_t)v4[j];
            *(half4v*)(pcs + (size_t)(qbase + q) * 256 + rd * 64 + dc * 4) = h4;
        }
    }
    if (quad == 0) {
        #pragma unroll
        for (int ct = 0; ct < 2; ++ct) {
            const size_t row = qbase + ct * 16 + l15;
            pm[(size_t)ks * NROWS + row] = m_c[ct];
            pl[(size_t)ks * NROWS + row] = l_c[ct];
        }
    }
}

// ---------------------------------------------------------------------------
// Kernel 4: merge the KS k-split partials.
// ---------------------------------------------------------------------------
__global__ __launch_bounds__(256) void combine_kernel(
    const half_t* __restrict__ pc, const float* __restrict__ pm,
    const float* __restrict__ pl, float* __restrict__ out)
{
    const int t = threadIdx.x;
    const int row = blockIdx.x * 4 + (t >> 6);
    const int d0 = (t & 63) * 4;
    float m[KS], l[KS];
    float ms = -1e30f;
    #pragma unroll
    for (int i = 0; i < KS; ++i) {
        m[i] = pm[(size_t)i * NROWS + row];
        l[i] = pl[(size_t)i * NROWS + row];
        ms = fmaxf(ms, m[i]);
    }
    float w[KS], tot = 0.f;
    #pragma unroll
    for (int i = 0; i < KS; ++i) {
        w[i] = l[i] * __expf(m[i] - ms);
        tot += w[i];
    }
    float inv = 1.0f / tot;
    float4_ o = {0.f, 0.f, 0.f, 0.f};
    #pragma unroll
    for (int i = 0; i < KS; ++i) {
        half4v y = *(const half4v*)(pc + ((size_t)i * NROWS + row) * 256 + d0);
        float wi = w[i] * inv;
        #pragma unroll
        for (int j = 0; j < 4; ++j) o[j] += wi * (float)y[j];
    }
    *(float4_*)(out + (size_t)row * 256 + d0) = o;
}

// ---------------------------------------------------------------------------
extern "C" void kernel_launch(void* const* d_in, const int* in_sizes, int n_in,
                              void* d_out, int out_size, void* d_ws, size_t ws_size,
                              hipStream_t stream) {
    const float* x      = (const float*)d_in[0];
    const float* states = (const float*)d_in[1];
    const float* Wq     = (const float*)d_in[2];
    const float* bq     = (const float*)d_in[3];
    const float* Wk     = (const float*)d_in[4];
    const float* bk     = (const float*)d_in[5];
    const float* Wv     = (const float*)d_in[6];
    const float* bv     = (const float*)d_in[7];
    const float* Wa     = (const float*)d_in[8];
    const float* ba     = (const float*)d_in[9];
    float* out = (float*)d_out;

    char* ws = (char*)d_ws;
    size_t off = 0;
    auto alloc = [&](size_t bytes) -> void* {
        void* p = ws + off;
        off += (bytes + 255) & ~(size_t)255;
        return p;
    };
    half_t* Wq_hi = (half_t*)alloc(65536 * 2);
    half_t* Wq_lo = (half_t*)alloc(65536 * 2);
    half_t* Wc_hi = (half_t*)alloc(65536 * 2);
    half_t* Wc_lo = (half_t*)alloc(65536 * 2);
    half_t* Wv_hi = (half_t*)alloc(65536 * 2);
    float*  bc    = (float*)alloc(256 * 4);
    half_t* q_hi  = (half_t*)alloc((size_t)NROWS * 256 * 2);
    half_t* wk_hi = (half_t*)alloc((size_t)NROWS * 256 * 2);   // tiled layout
    half_t* wk_lo = (half_t*)alloc((size_t)NROWS * 256 * 2);   // tiled layout
    half_t* vT    = (half_t*)alloc((size_t)NROWS * 256 * 2);   // tiled layout
    half_t* pc    = (half_t*)alloc((size_t)KS * NROWS * 256 * 2);
    float*  pm    = (float*)alloc((size_t)KS * NROWS * 4);
    float*  pl    = (float*)alloc((size_t)KS * NROWS * 4);

    prep_kernel<<<256, 256, 0, stream>>>(Wq, Wk, Wv, Wa, bk, ba,
                                         Wq_hi, Wq_lo, Wc_hi, Wc_lo, Wv_hi, bc);
    linear_kernel<<<768, 256, 0, stream>>>(x, states,
                                           Wq_hi, Wq_lo, bq,
                                           Wc_hi, Wc_lo, bc,
                                           Wv_hi, bv,
                                           q_hi, wk_hi, wk_lo, vT);
    attn_kernel<<<8 * 16 * KS, 256, 0, stream>>>(q_hi, wk_hi, wk_lo, vT,
                                                 pc, pm, pl);
    combine_kernel<<<NROWS / 4, 256, 0, stream>>>(pc, pm, pl, out);
}

// Round 3
// 207.598 us; speedup vs baseline: 1.0833x; 1.0605x over previous
//
#include <hip/hip_runtime.h>
#include <cstdint>
#include <cstddef>

typedef _Float16 half_t;
typedef _Float16 half8 __attribute__((ext_vector_type(8)));
typedef _Float16 half4v __attribute__((ext_vector_type(4)));
typedef float float4_ __attribute__((ext_vector_type(4)));

#define NB 8
#define SEQ 2048
#define DIM 256
#define NROWS (NB*SEQ)   // 16384
#define KS 4             // k-split -> grid 512 = 2 blocks/CU
#define NIT 16           // (2048/KS)/32 key-tiles per block

// async global->LDS DMA, 16B per lane; LDS dest = wave-uniform base + lane*16
__device__ __forceinline__ void dma16(const half_t* g, half_t* l) {
    __builtin_amdgcn_global_load_lds(
        (const __attribute__((address_space(1))) void*)g,
        (__attribute__((address_space(3))) void*)l,
        16, 0, 0);
}

// ---------------------------------------------------------------------------
// Kernel 1: fold Wc = Wa @ Wk, bc = Wa @ bk + ba; split weights to fp16 hi/lo
// ---------------------------------------------------------------------------
__global__ __launch_bounds__(256) void prep_kernel(
    const float* __restrict__ Wq, const float* __restrict__ Wk,
    const float* __restrict__ Wv, const float* __restrict__ Wa,
    const float* __restrict__ bk, const float* __restrict__ ba,
    half_t* __restrict__ Wq_hi, half_t* __restrict__ Wq_lo,
    half_t* __restrict__ Wc_hi, half_t* __restrict__ Wc_lo,
    half_t* __restrict__ Wv_hi, float* __restrict__ bc)
{
    const int e = blockIdx.x;
    const int d = threadIdx.x;
    const int idx = e * 256 + d;
    float acc = 0.f;
    for (int m = 0; m < 256; ++m)
        acc += Wa[e * 256 + m] * Wk[m * 256 + d];
    half_t h = (half_t)acc;
    Wc_hi[idx] = h;
    Wc_lo[idx] = (half_t)(acc - (float)h);
    float wq = Wq[idx];
    h = (half_t)wq;
    Wq_hi[idx] = h;
    Wq_lo[idx] = (half_t)(wq - (float)h);
    Wv_hi[idx] = (half_t)Wv[idx];
    if (d == 0) {
        float bacc = ba[e];
        for (int m = 0; m < 256; ++m) bacc += Wa[e * 256 + m] * bk[m];
        bc[e] = bacc;
    }
}

// ---------------------------------------------------------------------------
// Kernel 2: linears. seg0: q hi only. seg1: wk hi/lo in attn-tile-swizzled
// global layout. seg2: v -> vT tile-swizzled + key-permuted for reg-P PV.
// launch_bounds(256,2): cap regs at 256 -> 2 blocks/CU for phase overlap.
// ---------------------------------------------------------------------------
__global__ __launch_bounds__(256, 2) void linear_kernel(
    const float* __restrict__ x, const float* __restrict__ states,
    const half_t* __restrict__ Wq_hi, const half_t* __restrict__ Wq_lo, const float* __restrict__ bq,
    const half_t* __restrict__ Wc_hi, const half_t* __restrict__ Wc_lo, const float* __restrict__ bc,
    const half_t* __restrict__ Wv_hi, const float* __restrict__ bv,
    half_t* __restrict__ q_hi,
    half_t* __restrict__ wk_hi, half_t* __restrict__ wk_lo,
    half_t* __restrict__ vT)
{
    __shared__ half_t sB[2 * 64 * 256];   // weights hi+lo = 64 KiB; reused as repack buf
    half_t* sBh = sB;
    half_t* sBl = sB + 64 * 256;

    const int seg  = blockIdx.x >> 8;      // 0:q 1:wk 2:v
    const int t    = blockIdx.x & 255;
    const int tid  = threadIdx.x;
    const int lane = tid & 63;
    const int wv   = tid >> 6;
    const int quad = lane >> 4;
    const int l15  = lane & 15;
    const int rb   = t * 64;               // block row base
    const int r0   = rb + wv * 16;         // wave's 16 rows

    const float* src  = (seg == 0) ? x : states;
    const half_t* Bh  = (seg == 0) ? Wq_hi : (seg == 1) ? Wc_hi : Wv_hi;
    const half_t* Bl  = (seg == 0) ? Wq_lo : Wc_lo;
    const float* bias = (seg == 0) ? bq : (seg == 1) ? bc : bv;

    // A-frags direct from global: A[m=l15 -> row][k=c*32+quad*8+j], hi/lo split
    half8 ah[8], al[8];
    #pragma unroll
    for (int c = 0; c < 8; ++c) {
        const float* pa = src + (size_t)(r0 + l15) * 256 + c * 32 + quad * 8;
        float4_ u0 = *(const float4_*)pa;
        float4_ u1 = *(const float4_*)(pa + 4);
        #pragma unroll
        for (int j = 0; j < 4; ++j) {
            half_t hh = (half_t)u0[j];
            ah[c][j] = hh; al[c][j] = (half_t)(u0[j] - (float)hh);
            hh = (half_t)u1[j];
            ah[c][4 + j] = hh; al[c][4 + j] = (half_t)(u1[j] - (float)hh);
        }
    }

    float4_ acc[16];
    if (seg != 2) {
        #pragma unroll
        for (int nt = 0; nt < 16; ++nt) {
            float be = bias[nt * 16 + l15];
            acc[nt] = {be, be, be, be};
        }
    } else {
        #pragma unroll
        for (int et = 0; et < 16; ++et)
            #pragma unroll
            for (int r = 0; r < 4; ++r)
                acc[et][r] = bias[et * 16 + quad * 4 + r];
    }

    #pragma unroll
    for (int eg = 0; eg < 4; ++eg) {
        __syncthreads();
        // stage weights e-group [64 e][256 k], XOR-swizzled chunks
        #pragma unroll
        for (int i = 0; i < 8; ++i) {
            int g = tid + i * 256;             // 0..2047 chunks
            int e = g >> 5, c = g & 31;
            *(half8*)(sBh + e * 256 + ((c ^ (e & 7)) * 8)) =
                *(const half8*)(Bh + (size_t)(eg * 64 + e) * 256 + c * 8);
        }
        if (seg != 2) {
            #pragma unroll
            for (int i = 0; i < 8; ++i) {
                int g = tid + i * 256;
                int e = g >> 5, c = g & 31;
                *(half8*)(sBl + e * 256 + ((c ^ (e & 7)) * 8)) =
                    *(const half8*)(Bl + (size_t)(eg * 64 + e) * 256 + c * 8);
            }
        }
        __syncthreads();

        if (seg != 2) {
            #pragma unroll
            for (int ntl = 0; ntl < 4; ++ntl) {
                float4_ a = acc[eg * 4 + ntl];
                const int el = ntl * 16 + l15;
                #pragma unroll
                for (int c = 0; c < 8; ++c) {
                    int off = el * 256 + (((c * 4 + quad) ^ (el & 7)) * 8);
                    half8 bh = *(const half8*)(sBh + off);
                    half8 bl = *(const half8*)(sBl + off);
                    a = __builtin_amdgcn_mfma_f32_16x16x32_f16(ah[c], bh, a, 0, 0, 0);
                    a = __builtin_amdgcn_mfma_f32_16x16x32_f16(al[c], bh, a, 0, 0, 0);
                    a = __builtin_amdgcn_mfma_f32_16x16x32_f16(ah[c], bl, a, 0, 0, 0);
                }
                acc[eg * 4 + ntl] = a;
            }
        } else {
            // flipped: A = Wv tile (rows e), B = x rows -> D[e][row]
            #pragma unroll
            for (int ntl = 0; ntl < 4; ++ntl) {
                float4_ a = acc[eg * 4 + ntl];
                const int el = ntl * 16 + l15;
                #pragma unroll
                for (int c = 0; c < 8; ++c) {
                    int off = el * 256 + (((c * 4 + quad) ^ (el & 7)) * 8);
                    half8 aw = *(const half8*)(sBh + off);
                    a = __builtin_amdgcn_mfma_f32_16x16x32_f16(aw, ah[c], a, 0, 0, 0);
                }
                acc[eg * 4 + ntl] = a;
            }
        }
    }

    // epilogue: repack through LDS for coalesced half8 global stores
    __syncthreads();   // weights LDS no longer needed
    if (seg != 2) {
        half_t* R = sB;   // [64 rows][256]
        #pragma unroll
        for (int nt = 0; nt < 16; ++nt)
            #pragma unroll
            for (int r = 0; r < 4; ++r)
                R[(wv * 16 + quad * 4 + r) * 256 + nt * 16 + l15] = (half_t)acc[nt][r];
        __syncthreads();
        if (seg == 0) {
            // q hi only, row-major
            for (int i = 0; i < 8; ++i) {
                int g = tid + i * 256;                 // 2048 chunks
                int row = g >> 5, cc = g & 31;
                *(half8*)(q_hi + (size_t)(rb + row) * 256 + cc * 8) =
                    *(const half8*)(R + row * 256 + cc * 8);
            }
        } else {
            // wk hi: tile-swizzled layout (tile=32 keys, 8192 elems)
            for (int i = 0; i < 8; ++i) {
                int g = tid + i * 256;
                int row = g >> 5, cc = g & 31;
                int s = row & 31;
                size_t dst = ((size_t)(rb + row) >> 5) * 8192 + s * 256 + ((cc ^ (s & 7)) * 8);
                *(half8*)(wk_hi + dst) = *(const half8*)(R + row * 256 + cc * 8);
            }
            __syncthreads();
            #pragma unroll
            for (int nt = 0; nt < 16; ++nt)
                #pragma unroll
                for (int r = 0; r < 4; ++r) {
                    float v = acc[nt][r];
                    half_t hh = (half_t)v;
                    R[(wv * 16 + quad * 4 + r) * 256 + nt * 16 + l15] = (half_t)(v - (float)hh);
                }
            __syncthreads();
            for (int i = 0; i < 8; ++i) {
                int g = tid + i * 256;
                int row = g >> 5, cc = g & 31;
                int s = row & 31;
                size_t dst = ((size_t)(rb + row) >> 5) * 8192 + s * 256 + ((cc ^ (s & 7)) * 8);
                *(half8*)(wk_lo + dst) = *(const half8*)(R + row * 256 + cc * 8);
            }
        }
    } else {
        // vT repack: sV [d 256][s 64] stride 68, then tile-swizzled stores.
        // Key permutation: logical chunk q of a 32-key tile holds keys
        // {t32+4q+j}(j<4) and {t32+16+4q+(j-4)}(j>=4) -- matches the natural
        // per-lane P ownership of the attn QK^T output.
        half_t* sV = sB;
        #pragma unroll
        for (int et = 0; et < 16; ++et)
            #pragma unroll
            for (int r = 0; r < 4; ++r)
                sV[(et * 16 + quad * 4 + r) * 68 + wv * 16 + l15] = (half_t)acc[et][r];
        __syncthreads();
        const int b = rb >> 11, s0 = rb & 2047;
        for (int i = 0; i < 8; ++i) {
            int g = tid + i * 256;                 // 2048 chunks: d 256 x sc8 8
            int d = g >> 3, sc8 = g & 7;
            int kt = (s0 >> 5) + (sc8 >> 2);
            int q  = sc8 & 3;                      // logical key-chunk
            int t32 = (sc8 >> 2) * 32;
            int slot = q ^ (d & 3) ^ ((d >> 2) & 3);
            half4v a4 = *(const half4v*)(sV + d * 68 + t32 + q * 4);
            half4v b4 = *(const half4v*)(sV + d * 68 + t32 + 16 + q * 4);
            half8 hv;
            hv[0] = a4[0]; hv[1] = a4[1]; hv[2] = a4[2]; hv[3] = a4[3];
            hv[4] = b4[0]; hv[5] = b4[1]; hv[6] = b4[2]; hv[7] = b4[3];
            size_t dst = ((size_t)b * 64 + kt) * 8192 + d * 32 + slot * 8;
            *(half8*)(vT + dst) = hv;
        }
    }
}

// ---------------------------------------------------------------------------
// Kernel 3: flash attention, top-issue pipelined staging.
// LDS 64K: WKH dbuf (2x16K) + WKL single (16K) + VT single (16K).
//   - hi(it+1) + vt(it) issued at TOP of iter (targets certified free by the
//     previous iteration's barriers): hi gets a FULL iteration of cover,
//     vt gets QK+softmax of cover.
//   - lo(it+1) issued after barrier B (QK-done cert): cover = PV phase.
//     Only 4 ops on the short-cover path (was 8).
//   - 3 barriers/iter, every wait sits behind ample cover; never vmcnt(0)
//     in steady state.
// ---------------------------------------------------------------------------
__global__ __launch_bounds__(256, 2) void attn_kernel(
    const half_t* __restrict__ q_hi,
    const half_t* __restrict__ wk_hi, const half_t* __restrict__ wk_lo,
    const half_t* __restrict__ vT,
    half_t* __restrict__ pc, float* __restrict__ pm, float* __restrict__ pl)
{
    __shared__ __align__(16) unsigned char smem[64 * 1024];
    // WKH[0] @0, WKH[1] @16384, WKL @32768, VT @49152
    half_t* s_wk_lo = (half_t*)(smem + 32768);
    half_t* s_vt    = (half_t*)(smem + 49152);
    float*  scr     = (float*)smem;                   // epilogue overlay

    const int tid  = threadIdx.x;
    const int lane = tid & 63;
    const int wv   = tid >> 6;
    const int quad = lane >> 4;
    const int l15  = lane & 15;

    const int b  = blockIdx.x & 7;          // XCD-swizzle: batch per XCD
    const int qt = (blockIdx.x >> 3) & 15;  // q-tile 0..15 (128 rows each)
    const int ks = blockIdx.x >> 7;         // k-split quarter 0..3

    const int qbase = b * 2048 + qt * 128 + wv * 32;   // wave's 32 q-rows

    // q B-frags resident (hi plane only): B[n=qcol][k=c*32+quad*8+j]
    half8 qf[2][8];
    #pragma unroll
    for (int ct = 0; ct < 2; ++ct)
        #pragma unroll
        for (int c = 0; c < 8; ++c)
            qf[ct][c] = *(const half8*)(q_hi +
                (size_t)(qbase + ct * 16 + l15) * 256 + c * 32 + quad * 8);

    float4_ ctx[16][2];
    #pragma unroll
    for (int dt = 0; dt < 16; ++dt) {
        ctx[dt][0] = {0.f, 0.f, 0.f, 0.f};
        ctx[dt][1] = {0.f, 0.f, 0.f, 0.f};
    }
    float m_c[2] = {-1e30f, -1e30f};
    float l_c[2] = {0.f, 0.f};

    const half_t* wkh_b = wk_hi + (size_t)b * 64 * 8192;  // tiled layout
    const half_t* wkl_b = wk_lo + (size_t)b * 64 * 8192;
    const half_t* vt_b  = vT    + (size_t)b * 64 * 8192;
    const int t0 = ks * NIT;

    // prologue: stage hi(0)->WKH[0], lo(0)->WKL (no wait; loop top handles)
    {
        const half_t* wh_t = wkh_b + (size_t)t0 * 8192;
        const half_t* wl_t = wkl_b + (size_t)t0 * 8192;
        const int sg = wv;                 // 4 segs of 4 KiB each (per wave 1)
        #pragma unroll
        for (int i = 0; i < 4; ++i) {
            const int s4 = i * 4 + wv;     // 16 segments of 1 KiB
            dma16(wh_t + s4 * 512 + lane * 8, (half_t*)smem + s4 * 512);
            dma16(wl_t + s4 * 512 + lane * 8, s_wk_lo + s4 * 512);
        }
        (void)sg;
    }

    for (int it = 0; it < NIT; ++it) {
        half_t* wkh_cur = (half_t*)(smem + ((it & 1) << 14));
        half_t* wkh_nxt = (half_t*)(smem + (((it & 1) ^ 1) << 14));
        const bool pre = (it + 1 < NIT);

        // ---- top issues: vt(it) -> VT, hi(it+1) -> WKH[p^1]
        {
            const half_t* vt_t = vt_b + (size_t)(t0 + it) * 8192;
            #pragma unroll
            for (int i = 0; i < 4; ++i) {
                const int s4 = i * 4 + wv;
                dma16(vt_t + s4 * 512 + lane * 8, s_vt + s4 * 512);
            }
        }
        if (pre) {
            const half_t* wh_t = wkh_b + (size_t)(t0 + it + 1) * 8192;
            #pragma unroll
            for (int i = 0; i < 4; ++i) {
                const int s4 = i * 4 + wv;
                dma16(wh_t + s4 * 512 + lane * 8, wkh_nxt + s4 * 512);
            }
        }
        // drain lo(it) (and any older); keep vt(it) [+ hi(it+1)] in flight
        if (pre) asm volatile("s_waitcnt vmcnt(8)" ::: "memory");
        else     asm volatile("s_waitcnt vmcnt(4)" ::: "memory");
        __builtin_amdgcn_s_barrier();        // (A) wk(it) fully resident
        asm volatile("" ::: "memory");

        // ---- S^T = wk . q^T : tiles [kt 16-keys][ct 16-qcols], hi/lo on wk
        float4_ S[2][2];
        S[0][0] = {0.f,0.f,0.f,0.f}; S[0][1] = {0.f,0.f,0.f,0.f};
        S[1][0] = {0.f,0.f,0.f,0.f}; S[1][1] = {0.f,0.f,0.f,0.f};
        __builtin_amdgcn_s_setprio(1);
        #pragma unroll
        for (int c = 0; c < 8; ++c)
            #pragma unroll
            for (int kt = 0; kt < 2; ++kt) {
                const int key = kt * 16 + l15;
                const int off = key * 256 + (((c * 4 + quad) ^ (key & 7)) * 8);
                half8 wh = *(const half8*)(wkh_cur + off);
                half8 wl = *(const half8*)(s_wk_lo + off);
                #pragma unroll
                for (int ct = 0; ct < 2; ++ct) {
                    S[kt][ct] = __builtin_amdgcn_mfma_f32_16x16x32_f16(wh, qf[ct][c], S[kt][ct], 0, 0, 0);
                    S[kt][ct] = __builtin_amdgcn_mfma_f32_16x16x32_f16(wl, qf[ct][c], S[kt][ct], 0, 0, 0);
                }
            }
        __builtin_amdgcn_s_setprio(0);
        __builtin_amdgcn_sched_barrier(0);   // pin QK cluster + its lgkm waits

        // ---- softmax (VALU, overlaps DMA flight); lane owns qcol ct*16+l15
        float mx0, mx1;
        {
            float a0 = fmaxf(fmaxf(S[0][0][0], S[0][0][1]), fmaxf(S[0][0][2], S[0][0][3]));
            float b0 = fmaxf(fmaxf(S[1][0][0], S[1][0][1]), fmaxf(S[1][0][2], S[1][0][3]));
            mx0 = fmaxf(a0, b0);
            mx0 = fmaxf(mx0, __shfl_xor(mx0, 16));
            mx0 = fmaxf(mx0, __shfl_xor(mx0, 32));
            float a1 = fmaxf(fmaxf(S[0][1][0], S[0][1][1]), fmaxf(S[0][1][2], S[0][1][3]));
            float b1 = fmaxf(fmaxf(S[1][1][0], S[1][1][1]), fmaxf(S[1][1][2], S[1][1][3]));
            mx1 = fmaxf(a1, b1);
            mx1 = fmaxf(mx1, __shfl_xor(mx1, 16));
            mx1 = fmaxf(mx1, __shfl_xor(mx1, 32));
        }
        // defer-rescale: keep frozen max while tile max within THR=8
        const int doresc = __any((mx0 > m_c[0] + 8.f) || (mx1 > m_c[1] + 8.f));
        float alpha0 = 1.f, alpha1 = 1.f;
        if (doresc) {
            float mn0 = fmaxf(m_c[0], mx0);
            float mn1 = fmaxf(m_c[1], mx1);
            alpha0 = __expf(m_c[0] - mn0);
            alpha1 = __expf(m_c[1] - mn1);
            m_c[0] = mn0; m_c[1] = mn1;
        }
        // P stays in registers: pf[ct] is directly the PV B-frag (producer-side
        // key permutation of vT).
        half8 pf[2];
        #pragma unroll
        for (int ct = 0; ct < 2; ++ct) {
            const float mm = m_c[ct];
            float rs = 0.f;
            #pragma unroll
            for (int r = 0; r < 4; ++r) {
                float p0 = __expf(S[0][ct][r] - mm);
                float p1 = __expf(S[1][ct][r] - mm);
                rs += p0 + p1;
                pf[ct][r]     = (half_t)p0;
                pf[ct][4 + r] = (half_t)p1;
            }
            rs += __shfl_xor(rs, 16);
            rs += __shfl_xor(rs, 32);
            l_c[ct] = l_c[ct] * (ct ? alpha1 : alpha0) + rs;
        }
        if (doresc) {
            #pragma unroll
            for (int dt = 0; dt < 16; ++dt)
                #pragma unroll
                for (int r = 0; r < 4; ++r) {
                    ctx[dt][0][r] *= alpha0;
                    ctx[dt][1][r] *= alpha1;
                }
        }

        // drain vt(it) (issued at top, cover = QK+softmax); keep hi(it+1)
        if (pre) asm volatile("s_waitcnt vmcnt(4)" ::: "memory");
        else     asm volatile("s_waitcnt vmcnt(0)" ::: "memory");
        __builtin_amdgcn_s_barrier();        // (B) VT published; QK(it) done
        asm volatile("" ::: "memory");

        // lo(it+1): WKL overwrite safe (B certified QK done); cover = PV
        if (pre) {
            const half_t* wl_t = wkl_b + (size_t)(t0 + it + 1) * 8192;
            #pragma unroll
            for (int i = 0; i < 4; ++i) {
                const int s4 = i * 4 + wv;
                dma16(wl_t + s4 * 512 + lane * 8, s_wk_lo + s4 * 512);
            }
        }

        // ---- ctx^T += vT_tile . P^T
        __builtin_amdgcn_s_setprio(1);
        #pragma unroll
        for (int dt = 0; dt < 16; ++dt) {
            const int d = dt * 16 + l15;
            half8 vf = *(const half8*)(s_vt + d * 32 + ((quad ^ (d & 3) ^ ((d >> 2) & 3)) * 8));
            ctx[dt][0] = __builtin_amdgcn_mfma_f32_16x16x32_f16(vf, pf[0], ctx[dt][0], 0, 0, 0);
            ctx[dt][1] = __builtin_amdgcn_mfma_f32_16x16x32_f16(vf, pf[1], ctx[dt][1], 0, 0, 0);
        }
        __builtin_amdgcn_s_setprio(0);
        __builtin_amdgcn_sched_barrier(0);   // pin PV cluster + its lgkm waits
        __builtin_amdgcn_s_barrier();        // (C) PV done -> VT free next top
        asm volatile("" ::: "memory");
    }

    // epilogue: normalized partial context (fp16) via per-wave LDS transpose.
    // Barrier (C) of the last iteration guarantees all waves are past PV,
    // and the last iteration's waits drained all DMA (vmcnt(0) pre-B).
    float rinv[2] = {1.0f / l_c[0], 1.0f / l_c[1]};
    float* sw = scr + wv * (32 * 68);       // [q 32][stride 68] f32
    half_t* pcs = pc + (size_t)ks * NROWS * 256;
    #pragma unroll
    for (int rd = 0; rd < 4; ++rd) {
        #pragma unroll
        for (int dtl = 0; dtl < 4; ++dtl) {
            const int dt = rd * 4 + dtl;
            #pragma unroll
            for (int ct = 0; ct < 2; ++ct)
                #pragma unroll
                for (int r = 0; r < 4; ++r)
                    sw[(ct * 16 + l15) * 68 + dtl * 16 + quad * 4 + r] = ctx[dt][ct][r] * rinv[ct];
        }
        #pragma unroll
        for (int i = 0; i < 8; ++i) {
            int g = lane + i * 64;
            int q = g >> 4, dc = g & 15;
            float4_ v4 = *(const float4_*)(sw + q * 68 + dc * 4);
            half4v h4;
            #pragma unroll
            for (int j = 0; j < 4; ++j) h4[j] = (half_t)v4[j];
            *(half4v*)(pcs + (size_t)(qbase + q) * 256 + rd * 64 + dc * 4) = h4;
        }
    }
    if (quad == 0) {
        #pragma unroll
        for (int ct = 0; ct < 2; ++ct) {
            const size_t row = qbase + ct * 16 + l15;
            pm[(size_t)ks * NROWS + row] = m_c[ct];
            pl[(size_t)ks * NROWS + row] = l_c[ct];
        }
    }
}

// ---------------------------------------------------------------------------
// Kernel 4: merge the KS k-split partials.
// ---------------------------------------------------------------------------
__global__ __launch_bounds__(256) void combine_kernel(
    const half_t* __restrict__ pc, const float* __restrict__ pm,
    const float* __restrict__ pl, float* __restrict__ out)
{
    const int t = threadIdx.x;
    const int row = blockIdx.x * 4 + (t >> 6);
    const int d0 = (t & 63) * 4;
    float m[KS], l[KS];
    float ms = -1e30f;
    #pragma unroll
    for (int i = 0; i < KS; ++i) {
        m[i] = pm[(size_t)i * NROWS + row];
        l[i] = pl[(size_t)i * NROWS + row];
        ms = fmaxf(ms, m[i]);
    }
    float w[KS], tot = 0.f;
    #pragma unroll
    for (int i = 0; i < KS; ++i) {
        w[i] = l[i] * __expf(m[i] - ms);
        tot += w[i];
    }
    float inv = 1.0f / tot;
    float4_ o = {0.f, 0.f, 0.f, 0.f};
    #pragma unroll
    for (int i = 0; i < KS; ++i) {
        half4v y = *(const half4v*)(pc + ((size_t)i * NROWS + row) * 256 + d0);
        float wi = w[i] * inv;
        #pragma unroll
        for (int j = 0; j < 4; ++j) o[j] += wi * (float)y[j];
    }
    *(float4_*)(out + (size_t)row * 256 + d0) = o;
}

// ---------------------------------------------------------------------------
extern "C" void kernel_launch(void* const* d_in, const int* in_sizes, int n_in,
                              void* d_out, int out_size, void* d_ws, size_t ws_size,
                              hipStream_t stream) {
    const float* x      = (const float*)d_in[0];
    const float* states = (const float*)d_in[1];
    const float* Wq     = (const float*)d_in[2];
    const float* bq     = (const float*)d_in[3];
    const float* Wk     = (const float*)d_in[4];
    const float* bk     = (const float*)d_in[5];
    const float* Wv     = (const float*)d_in[6];
    const float* bv     = (const float*)d_in[7];
    const float* Wa     = (const float*)d_in[8];
    const float* ba     = (const float*)d_in[9];
    float* out = (float*)d_out;

    char* ws = (char*)d_ws;
    size_t off = 0;
    auto alloc = [&](size_t bytes) -> void* {
        void* p = ws + off;
        off += (bytes + 255) & ~(size_t)255;
        return p;
    };
    half_t* Wq_hi = (half_t*)alloc(65536 * 2);
    half_t* Wq_lo = (half_t*)alloc(65536 * 2);
    half_t* Wc_hi = (half_t*)alloc(65536 * 2);
    half_t* Wc_lo = (half_t*)alloc(65536 * 2);
    half_t* Wv_hi = (half_t*)alloc(65536 * 2);
    float*  bc    = (float*)alloc(256 * 4);
    half_t* q_hi  = (half_t*)alloc((size_t)NROWS * 256 * 2);
    half_t* wk_hi = (half_t*)alloc((size_t)NROWS * 256 * 2);   // tiled layout
    half_t* wk_lo = (half_t*)alloc((size_t)NROWS * 256 * 2);   // tiled layout
    half_t* vT    = (half_t*)alloc((size_t)NROWS * 256 * 2);   // tiled layout
    half_t* pc    = (half_t*)alloc((size_t)KS * NROWS * 256 * 2);
    float*  pm    = (float*)alloc((size_t)KS * NROWS * 4);
    float*  pl    = (float*)alloc((size_t)KS * NROWS * 4);

    prep_kernel<<<256, 256, 0, stream>>>(Wq, Wk, Wv, Wa, bk, ba,
                                         Wq_hi, Wq_lo, Wc_hi, Wc_lo, Wv_hi, bc);
    linear_kernel<<<768, 256, 0, stream>>>(x, states,
                                           Wq_hi, Wq_lo, bq,
                                           Wc_hi, Wc_lo, bc,
                                           Wv_hi, bv,
                                           q_hi, wk_hi, wk_lo, vT);
    attn_kernel<<<8 * 16 * KS, 256, 0, stream>>>(q_hi, wk_hi, wk_lo, vT,
                                                 pc, pm, pl);
    combine_kernel<<<NROWS / 4, 256, 0, stream>>>(pc, pm, pl, out);
}